// Round 1
// baseline (109.404 us; speedup 1.0000x reference)
//
#include <hip/hip_runtime.h>
#include <stdint.h>

// Problem constants (match reference)
#define NB   8
#define NC   256
#define NT   1024
#define NM   512
#define NNEG 100

// ---------------- Threefry-2x32-20 (JAX) ----------------
__device__ __forceinline__ unsigned rotl32(unsigned x, int d) {
  return (x << d) | (x >> (32 - d));
}

// bits for flat element i of jax.random.uniform(key(42), (8,512,512))
// N = 2^21 elements, split halves: i<half -> (x0=i, x1=i+half) take out0
//                                  i>=half -> (x0=i-half, x1=i) take out1
__device__ unsigned threefry_bits(unsigned i) {
  const unsigned half = 1048576u; // 2^20
  const bool lo = i < half;
  unsigned v0 = lo ? i : (i - half);
  unsigned v1 = lo ? (i + half) : i;
  const unsigned k0 = 0u, k1 = 42u;
  const unsigned k2 = k0 ^ k1 ^ 0x1BD11BDAu;
  v0 += k0; v1 += k1;
#define TF_R(r) { v0 += v1; v1 = rotl32(v1, r); v1 ^= v0; }
  TF_R(13) TF_R(15) TF_R(26) TF_R(6)
  v0 += k1; v1 += k2 + 1u;
  TF_R(17) TF_R(29) TF_R(16) TF_R(24)
  v0 += k2; v1 += k0 + 2u;
  TF_R(13) TF_R(15) TF_R(26) TF_R(6)
  v0 += k0; v1 += k1 + 3u;
  TF_R(17) TF_R(29) TF_R(16) TF_R(24)
  v0 += k1; v1 += k2 + 4u;
  TF_R(13) TF_R(15) TF_R(26) TF_R(6)
  v0 += k2; v1 += k0 + 5u;
#undef TF_R
  return lo ? v0 : v1;
}

// ---------------- Kernel 1: masked index extraction ----------------
// One block per batch row. Detects mask element storage width (1/4/8 bytes)
// from the first 1024 elements (always in-bounds: >= 8192-byte buffer),
// then prefix-sum compaction of masked timesteps (stable time order).
__global__ __launch_bounds__(1024) void k_idx(const void* __restrict__ maskp,
                                              int* __restrict__ idxp) {
  __shared__ int sc[1024];
  __shared__ int sflag;
  const int t = threadIdx.x;
  const int b = blockIdx.x;
  const unsigned char* mb = (const unsigned char*)maskp;

  // --- storage-width detection on row-0 region ---
  int c1 = (mb[t] != 0) ? 1 : 0;
  int c4 = (((const unsigned*)mb)[t] != 0u) ? 1 : 0;
  int c8 = (((const unsigned long long*)mb)[t] != 0ull) ? 1 : 0;
  sc[t] = c1 + (c4 << 11) + (c8 << 22);
  __syncthreads();
  for (int off = 512; off > 0; off >>= 1) {
    if (t < off) sc[t] += sc[t + off];
    __syncthreads();
  }
  if (t == 0) {
    int c1s = sc[0] & 2047, c4s = (sc[0] >> 11) & 2047, c8s = (sc[0] >> 22) & 2047;
    sflag = (c4s == 512) ? 4 : ((c1s == 512) ? 1 : ((c8s == 512) ? 8 : 4));
  }
  __syncthreads();
  const int stride = sflag;

  // --- read this row's mask bit ---
  const size_t e = (size_t)b * NT + t;
  int f;
  if (stride == 1)      f = (mb[e] != 0);
  else if (stride == 4) f = (((const unsigned*)mb)[e] != 0u);
  else                  f = (((const unsigned long long*)mb)[e] != 0ull);

  __syncthreads(); // done with sc from detection
  sc[t] = f;
  __syncthreads();
  // Hillis-Steele inclusive scan over 1024
  for (int off = 1; off < 1024; off <<= 1) {
    int v = sc[t];
    int add = (t >= off) ? sc[t - off] : 0;
    __syncthreads();
    sc[t] = v + add;
    __syncthreads();
  }
  if (f) idxp[b * NM + (sc[t] - 1)] = t;
}

// ---------------- Kernel 2: gathered Gram GEMM ----------------
// S[b][m][j] = sum_c ctx[b,c,t_m] * feat[b,c,t_j], m,j over masked columns.
// 64x64 output tile per 256-thread block; gather fused into LDS staging.
__global__ __launch_bounds__(256) void k_gemm(const float* __restrict__ ctx,
                                              const float* __restrict__ feat,
                                              const int* __restrict__ idxp,
                                              float* __restrict__ S) {
  __shared__ float At[16][68]; // [cc][mm], 68 pad -> 16B-aligned rows
  __shared__ float Bt[16][68];
  __shared__ int tA[64], tB[64];

  const int tid = threadIdx.x;
  const int b  = blockIdx.z;
  const int m0 = blockIdx.y * 64;
  const int j0 = blockIdx.x * 64;

  if (tid < 64)       tA[tid]      = idxp[b * NM + m0 + tid];
  else if (tid < 128) tB[tid - 64] = idxp[b * NM + j0 + (tid - 64)];
  __syncthreads();

  const float* cb = ctx  + (size_t)b * NC * NT;
  const float* fb = feat + (size_t)b * NC * NT;

  float acc[4][4];
#pragma unroll
  for (int i = 0; i < 4; ++i)
#pragma unroll
    for (int k = 0; k < 4; ++k) acc[i][k] = 0.f;

  const int ty = tid >> 4, tx = tid & 15;

  for (int c0 = 0; c0 < NC; c0 += 16) {
#pragma unroll
    for (int p = 0; p < 4; ++p) {
      int ee = tid + p * 256;
      int mm = ee & 63;
      int cc = ee >> 6;
      At[cc][mm] = cb[(size_t)(c0 + cc) * NT + tA[mm]];
      Bt[cc][mm] = fb[(size_t)(c0 + cc) * NT + tB[mm]];
    }
    __syncthreads();
#pragma unroll
    for (int cc = 0; cc < 16; ++cc) {
      float a0 = At[cc][ty * 4 + 0], a1 = At[cc][ty * 4 + 1];
      float a2 = At[cc][ty * 4 + 2], a3 = At[cc][ty * 4 + 3];
      float b0 = Bt[cc][tx * 4 + 0], b1 = Bt[cc][tx * 4 + 1];
      float b2 = Bt[cc][tx * 4 + 2], b3 = Bt[cc][tx * 4 + 3];
      acc[0][0] += a0 * b0; acc[0][1] += a0 * b1; acc[0][2] += a0 * b2; acc[0][3] += a0 * b3;
      acc[1][0] += a1 * b0; acc[1][1] += a1 * b1; acc[1][2] += a1 * b2; acc[1][3] += a1 * b3;
      acc[2][0] += a2 * b0; acc[2][1] += a2 * b1; acc[2][2] += a2 * b2; acc[2][3] += a2 * b3;
      acc[3][0] += a3 * b0; acc[3][1] += a3 * b1; acc[3][2] += a3 * b2; acc[3][3] += a3 * b3;
    }
    __syncthreads();
  }

#pragma unroll
  for (int i = 0; i < 4; ++i) {
    float4 v = make_float4(acc[i][0], acc[i][1], acc[i][2], acc[i][3]);
    *(float4*)&S[((size_t)b * NM + m0 + ty * 4 + i) * NM + j0 + tx * 4] = v;
  }
}

// ---------------- Kernel 3: scores + top-100 + loss partials ----------------
// One block per (b,m) row: threefry scores, bitonic sort (desc via asc sort,
// take top), gather 101 logits from S row, serial softmax/tanh by thread 0.
__global__ __launch_bounds__(512) void k_loss(const float* __restrict__ S,
                                              float* __restrict__ pl,
                                              float* __restrict__ pa) {
  __shared__ unsigned long long skey[512];
  __shared__ float logit[101];
  const int t = threadIdx.x;
  const int row = blockIdx.x;  // b*512 + m
  const int m = row & (NM - 1);

  // uniform score monotone in u = bits>>9 ; self -> key 0 (score -1 = lowest)
  unsigned bits = threefry_bits((unsigned)row * 512u + (unsigned)t);
  unsigned u = bits >> 9;
  unsigned long long key =
      (t == m) ? 0ull
               : ((((unsigned long long)u + 1ull) << 10) |
                  (unsigned long long)(1023 - t)); // tie -> lower index first
  skey[t] = key;
  __syncthreads();

  // ascending bitonic sort of 512 keys
  for (unsigned k = 2; k <= 512; k <<= 1) {
    for (unsigned jj = k >> 1; jj > 0; jj >>= 1) {
      unsigned ixj = (unsigned)t ^ jj;
      if (ixj > (unsigned)t) {
        unsigned long long a = skey[t], bb = skey[ixj];
        bool up = ((t & k) == 0);
        if ((a > bb) == up) { skey[t] = bb; skey[ixj] = a; }
      }
      __syncthreads();
    }
  }

  const float* Srow = S + (size_t)row * NM;
  if (t < NNEG) {
    int j = 1023 - (int)(skey[511 - t] & 1023ull);
    logit[t + 1] = Srow[j];
  } else if (t == NNEG) {
    logit[0] = Srow[m]; // positive logit
  }
  __syncthreads();

  if (t == 0) {
    float mx = logit[0];
    for (int q = 1; q <= NNEG; ++q) mx = fmaxf(mx, logit[q]);
    float den = 0.f, aux = 0.f;
    for (int q = 0; q <= NNEG; ++q) {
      float l = logit[q];
      den += expf(l - mx);
      float th = tanhf(l);
      aux += th * th;
    }
    pl[row] = expf(logit[0] - mx) / den;
    pa[row] = aux;
  }
}

// ---------------- Kernel 4: deterministic final reduction ----------------
__global__ __launch_bounds__(1024) void k_red(const float* __restrict__ pl,
                                              const float* __restrict__ pa,
                                              float* __restrict__ out) {
  __shared__ float s1[1024], s2[1024];
  const int t = threadIdx.x;
  float a = 0.f, b = 0.f;
  for (int q = t; q < NB * NM; q += 1024) { a += pl[q]; b += pa[q]; }
  s1[t] = a; s2[t] = b;
  __syncthreads();
  for (int off = 512; off > 0; off >>= 1) {
    if (t < off) { s1[t] += s1[t + off]; s2[t] += s2[t + off]; }
    __syncthreads();
  }
  if (t == 0) { out[0] = s1[0]; out[1] = s2[0]; }
}

extern "C" void kernel_launch(void* const* d_in, const int* in_sizes, int n_in,
                              void* d_out, int out_size, void* d_ws, size_t ws_size,
                              hipStream_t stream) {
  const float* feat = (const float*)d_in[0];  // feat_proj [B,C,T]
  const void*  mask = d_in[1];                // mask [B,T] bool (width detected)
  const float* ctx  = (const float*)d_in[2];  // context_output [B,C,T]
  float* out = (float*)d_out;                 // [total_loss, total_aux_loss]

  char* ws = (char*)d_ws;
  int*   idxp = (int*)ws;                              // 16 KB
  float* S    = (float*)(ws + 16384);                  // 8 MB
  float* pl   = (float*)(ws + 16384 + (size_t)NB * NM * NM * 4); // 16 KB
  float* pa   = pl + NB * NM;                          // 16 KB

  k_idx<<<NB, 1024, 0, stream>>>(mask, idxp);

  dim3 g2(NM / 64, NM / 64, NB); // (j-tiles, m-tiles, b)
  k_gemm<<<g2, 256, 0, stream>>>(ctx, feat, idxp, S);

  k_loss<<<NB * NM, 512, 0, stream>>>(S, pl, pa);

  k_red<<<1, 1024, 0, stream>>>(pl, pa, out);
}

// Round 2
// 56.151 us; speedup vs baseline: 1.9484x; 1.9484x over previous
//
#include <hip/hip_runtime.h>
#include <stdint.h>

// Problem constants (match reference)
#define NB   8
#define NC   256
#define NT   1024
#define NM   512
#define NNEG 100

// ---------------- Threefry-2x32-20 (JAX) ----------------
__device__ __forceinline__ unsigned rotl32(unsigned x, int d) {
  return (x << d) | (x >> (32 - d));
}

// bits for flat element i of jax.random.uniform(key(42), (8,512,512))
__device__ unsigned threefry_bits(unsigned i) {
  const unsigned half = 1048576u; // 2^20
  const bool lo = i < half;
  unsigned v0 = lo ? i : (i - half);
  unsigned v1 = lo ? (i + half) : i;
  const unsigned k0 = 0u, k1 = 42u;
  const unsigned k2 = k0 ^ k1 ^ 0x1BD11BDAu;
  v0 += k0; v1 += k1;
#define TF_R(r) { v0 += v1; v1 = rotl32(v1, r); v1 ^= v0; }
  TF_R(13) TF_R(15) TF_R(26) TF_R(6)
  v0 += k1; v1 += k2 + 1u;
  TF_R(17) TF_R(29) TF_R(16) TF_R(24)
  v0 += k2; v1 += k0 + 2u;
  TF_R(13) TF_R(15) TF_R(26) TF_R(6)
  v0 += k0; v1 += k1 + 3u;
  TF_R(17) TF_R(29) TF_R(16) TF_R(24)
  v0 += k1; v1 += k2 + 4u;
  TF_R(13) TF_R(15) TF_R(26) TF_R(6)
  v0 += k2; v1 += k0 + 5u;
#undef TF_R
  return lo ? v0 : v1;
}

// ---------------- Kernel 1: masked index extraction ----------------
__global__ __launch_bounds__(1024) void k_idx(const void* __restrict__ maskp,
                                              int* __restrict__ idxp) {
  __shared__ int sc[1024];
  __shared__ int sflag;
  const int t = threadIdx.x;
  const int b = blockIdx.x;
  const unsigned char* mb = (const unsigned char*)maskp;

  int c1 = (mb[t] != 0) ? 1 : 0;
  int c4 = (((const unsigned*)mb)[t] != 0u) ? 1 : 0;
  int c8 = (((const unsigned long long*)mb)[t] != 0ull) ? 1 : 0;
  sc[t] = c1 + (c4 << 11) + (c8 << 22);
  __syncthreads();
  for (int off = 512; off > 0; off >>= 1) {
    if (t < off) sc[t] += sc[t + off];
    __syncthreads();
  }
  if (t == 0) {
    int c1s = sc[0] & 2047, c4s = (sc[0] >> 11) & 2047, c8s = (sc[0] >> 22) & 2047;
    sflag = (c4s == 512) ? 4 : ((c1s == 512) ? 1 : ((c8s == 512) ? 8 : 4));
  }
  __syncthreads();
  const int stride = sflag;

  const size_t e = (size_t)b * NT + t;
  int f;
  if (stride == 1)      f = (mb[e] != 0);
  else if (stride == 4) f = (((const unsigned*)mb)[e] != 0u);
  else                  f = (((const unsigned long long*)mb)[e] != 0ull);

  __syncthreads();
  sc[t] = f;
  __syncthreads();
  for (int off = 1; off < 1024; off <<= 1) {
    int v = sc[t];
    int add = (t >= off) ? sc[t - off] : 0;
    __syncthreads();
    sc[t] = v + add;
    __syncthreads();
  }
  if (f) idxp[b * NM + (sc[t] - 1)] = t;
}

// ---------------- Kernel 2: gathered Gram GEMM ----------------
__global__ __launch_bounds__(256) void k_gemm(const float* __restrict__ ctx,
                                              const float* __restrict__ feat,
                                              const int* __restrict__ idxp,
                                              float* __restrict__ S) {
  __shared__ float At[16][68];
  __shared__ float Bt[16][68];
  __shared__ int tA[64], tB[64];

  const int tid = threadIdx.x;
  const int b  = blockIdx.z;
  const int m0 = blockIdx.y * 64;
  const int j0 = blockIdx.x * 64;

  if (tid < 64)       tA[tid]      = idxp[b * NM + m0 + tid];
  else if (tid < 128) tB[tid - 64] = idxp[b * NM + j0 + (tid - 64)];
  __syncthreads();

  const float* cb = ctx  + (size_t)b * NC * NT;
  const float* fb = feat + (size_t)b * NC * NT;

  float acc[4][4];
#pragma unroll
  for (int i = 0; i < 4; ++i)
#pragma unroll
    for (int k = 0; k < 4; ++k) acc[i][k] = 0.f;

  const int ty = tid >> 4, tx = tid & 15;

  for (int c0 = 0; c0 < NC; c0 += 16) {
#pragma unroll
    for (int p = 0; p < 4; ++p) {
      int ee = tid + p * 256;
      int mm = ee & 63;
      int cc = ee >> 6;
      At[cc][mm] = cb[(size_t)(c0 + cc) * NT + tA[mm]];
      Bt[cc][mm] = fb[(size_t)(c0 + cc) * NT + tB[mm]];
    }
    __syncthreads();
#pragma unroll
    for (int cc = 0; cc < 16; ++cc) {
      float a0 = At[cc][ty * 4 + 0], a1 = At[cc][ty * 4 + 1];
      float a2 = At[cc][ty * 4 + 2], a3 = At[cc][ty * 4 + 3];
      float b0 = Bt[cc][tx * 4 + 0], b1 = Bt[cc][tx * 4 + 1];
      float b2 = Bt[cc][tx * 4 + 2], b3 = Bt[cc][tx * 4 + 3];
      acc[0][0] += a0 * b0; acc[0][1] += a0 * b1; acc[0][2] += a0 * b2; acc[0][3] += a0 * b3;
      acc[1][0] += a1 * b0; acc[1][1] += a1 * b1; acc[1][2] += a1 * b2; acc[1][3] += a1 * b3;
      acc[2][0] += a2 * b0; acc[2][1] += a2 * b1; acc[2][2] += a2 * b2; acc[2][3] += a2 * b3;
      acc[3][0] += a3 * b0; acc[3][1] += a3 * b1; acc[3][2] += a3 * b2; acc[3][3] += a3 * b3;
    }
    __syncthreads();
  }

#pragma unroll
  for (int i = 0; i < 4; ++i) {
    float4 v = make_float4(acc[i][0], acc[i][1], acc[i][2], acc[i][3]);
    *(float4*)&S[((size_t)b * NM + m0 + ty * 4 + i) * NM + j0 + tx * 4] = v;
  }
}

// ---------------- Kernel 3: histogram top-100 + parallel loss ----------------
// One block (512 thr) per (b,m) row. Threefry key per candidate; 256-bin
// histogram + wave suffix-scan finds the top-100 threshold bin; boundary bin
// resolved serially (expected ~2 entries). Softmax/tanh fully parallel with
// wave shuffle reductions. Only the SET of top-100 matters (outputs are
// order-independent sums), so no sort is needed.
__global__ __launch_bounds__(512) void k_loss(const float* __restrict__ S,
                                              float* __restrict__ pl,
                                              float* __restrict__ pa) {
  __shared__ unsigned hist[256];
  __shared__ unsigned long long bkey[512]; // boundary-bin candidates, (key<<1)|1
  __shared__ int bcount;
  __shared__ int boundary_bin, need_s;
  __shared__ unsigned char selflag[512];
  __shared__ float redM[8], redE[8], redA[8];
  __shared__ float posnum;

  const int t = threadIdx.x;
  const int row = blockIdx.x;  // b*512 + m
  const int m = row & (NM - 1);
  const bool self = (t == m);

  // key: monotone in uniform score, tie -> lower index wins; unique per t
  unsigned bits = threefry_bits((unsigned)row * 512u + (unsigned)t);
  unsigned u = bits >> 9;                       // 23-bit
  unsigned key = (u << 9) | (unsigned)(511 - t);
  int bin = (int)(u >> 15);                     // top 8 bits -> 256 bins

  if (t < 256) hist[t] = 0;
  if (t == 0) bcount = 0;
  selflag[t] = 0;
  __syncthreads();

  if (!self) atomicAdd(&hist[bin], 1u);
  __syncthreads();

  // wave 0: suffix scan over 256 bins (4 bins/lane), find threshold bin
  if (t < 64) {
    unsigned h0 = hist[4 * t + 0], h1 = hist[4 * t + 1];
    unsigned h2 = hist[4 * t + 2], h3 = hist[4 * t + 3];
    unsigned s = h0 + h1 + h2 + h3;
    unsigned suf = s;
#pragma unroll
    for (int off = 1; off < 64; off <<= 1) {
      unsigned o = __shfl_down(suf, off, 64);
      if (t + off < 64) suf += o;
    }
    // suf = sum over lanes >= t
    unsigned a3 = suf - s;       // count in bins > 4t+3
    unsigned a2 = a3 + h3;
    unsigned a1 = a2 + h2;
    unsigned a0 = a1 + h1;
    if (a3 < NNEG && a3 + h3 >= NNEG) { boundary_bin = 4 * t + 3; need_s = NNEG - (int)a3; }
    if (a2 < NNEG && a2 + h2 >= NNEG) { boundary_bin = 4 * t + 2; need_s = NNEG - (int)a2; }
    if (a1 < NNEG && a1 + h1 >= NNEG) { boundary_bin = 4 * t + 1; need_s = NNEG - (int)a1; }
    if (a0 < NNEG && a0 + h0 >= NNEG) { boundary_bin = 4 * t + 0; need_s = NNEG - (int)a0; }
  }
  __syncthreads();

  const int bb = boundary_bin;
  if (!self) {
    if (bin > bb) selflag[t] = 1;
    else if (bin == bb) {
      int p = atomicAdd(&bcount, 1);
      bkey[p] = (((unsigned long long)key) << 1) | 1ull;
    }
  }
  __syncthreads();

  // resolve boundary bin serially (expected ~2 entries, need_s >= 1)
  if (t == 0) {
    int cnt = bcount, need = need_s;
    for (int it = 0; it < need; ++it) {
      unsigned long long best = 0ull; int bi = 0;
      for (int q = 0; q < cnt; ++q)
        if (bkey[q] > best) { best = bkey[q]; bi = q; }
      bkey[bi] = 0ull;
      int tt = 511 - (int)((best >> 1) & 511ull);
      selflag[tt] = 1;
    }
  }
  __syncthreads();

  // parallel softmax + tanh^2 over the 101-logit set
  const float* Srow = S + (size_t)row * NM;
  const bool act = (selflag[t] != 0) || self;
  const float logitv = Srow[t];                 // coalesced full-row read
  const int wid = t >> 6;

  float mv = act ? logitv : -3.4e38f;
#pragma unroll
  for (int off = 32; off > 0; off >>= 1) mv = fmaxf(mv, __shfl_xor(mv, off, 64));
  if ((t & 63) == 0) redM[wid] = mv;
  __syncthreads();
  float mx = redM[0];
#pragma unroll
  for (int q = 1; q < 8; ++q) mx = fmaxf(mx, redM[q]);

  float e = 0.f, a = 0.f;
  if (act) {
    e = expf(logitv - mx);
    float th = tanhf(logitv);
    a = th * th;
  }
  if (self) posnum = e;

  float es = e, as = a;
#pragma unroll
  for (int off = 32; off > 0; off >>= 1) {
    es += __shfl_xor(es, off, 64);
    as += __shfl_xor(as, off, 64);
  }
  if ((t & 63) == 0) { redE[wid] = es; redA[wid] = as; }
  __syncthreads();

  if (t == 0) {
    float den = 0.f, aux = 0.f;
#pragma unroll
    for (int q = 0; q < 8; ++q) { den += redE[q]; aux += redA[q]; }
    pl[row] = posnum / den;
    pa[row] = aux;
  }
}

// ---------------- Kernel 4: deterministic final reduction ----------------
__global__ __launch_bounds__(1024) void k_red(const float* __restrict__ pl,
                                              const float* __restrict__ pa,
                                              float* __restrict__ out) {
  __shared__ float s1[1024], s2[1024];
  const int t = threadIdx.x;
  float a = 0.f, b = 0.f;
  for (int q = t; q < NB * NM; q += 1024) { a += pl[q]; b += pa[q]; }
  s1[t] = a; s2[t] = b;
  __syncthreads();
  for (int off = 512; off > 0; off >>= 1) {
    if (t < off) { s1[t] += s1[t + off]; s2[t] += s2[t + off]; }
    __syncthreads();
  }
  if (t == 0) { out[0] = s1[0]; out[1] = s2[0]; }
}

extern "C" void kernel_launch(void* const* d_in, const int* in_sizes, int n_in,
                              void* d_out, int out_size, void* d_ws, size_t ws_size,
                              hipStream_t stream) {
  const float* feat = (const float*)d_in[0];  // feat_proj [B,C,T]
  const void*  mask = d_in[1];                // mask [B,T] bool
  const float* ctx  = (const float*)d_in[2];  // context_output [B,C,T]
  float* out = (float*)d_out;

  char* ws = (char*)d_ws;
  int*   idxp = (int*)ws;                              // 16 KB
  float* S    = (float*)(ws + 16384);                  // 8 MB
  float* pl   = (float*)(ws + 16384 + (size_t)NB * NM * NM * 4);
  float* pa   = pl + NB * NM;

  k_idx<<<NB, 1024, 0, stream>>>(mask, idxp);

  dim3 g2(NM / 64, NM / 64, NB);
  k_gemm<<<g2, 256, 0, stream>>>(ctx, feat, idxp, S);

  k_loss<<<NB * NM, 512, 0, stream>>>(S, pl, pa);

  k_red<<<1, 1024, 0, stream>>>(pl, pa, out);
}